// Round 20
// baseline (3526.881 us; speedup 1.0000x reference)
//
#include <hip/hip_runtime.h>
#include <hip/hip_bf16.h>

typedef _Float16 half8 __attribute__((ext_vector_type(8)));
typedef _Float16 h2 __attribute__((ext_vector_type(2)));
typedef float floatx4 __attribute__((ext_vector_type(4)));
typedef unsigned int uint;

__device__ __constant__ float NF4_TAB[16] = {
    -1.0f, -0.6961928009986877f, -0.5250730514526367f, -0.39491748809814453f,
    -0.28444138169288635f, -0.18477343022823334f, -0.09105003625154495f, 0.0f,
    0.07958029955625534f, 0.16093020141124725f, 0.24611230194568634f,
    0.33791524171829224f, 0.44070982933044434f, 0.5626170039176941f,
    0.7229568362236023f, 1.0f};

typedef __attribute__((address_space(3))) void lds_t;
typedef __attribute__((address_space(1))) void gbl_t;

__device__ __forceinline__ void gload16(const void* g, void* l) {
  __builtin_amdgcn_global_load_lds((gbl_t*)g, (lds_t*)l, 16, 0, 0);
}

#define FENCE() asm volatile("" ::: "memory")

#if __has_builtin(__builtin_amdgcn_perm)
#define PERM(a, b, s) __builtin_amdgcn_perm((a), (b), (s))
#else
__device__ __forceinline__ uint PERM(uint a, uint b, uint s) {
  unsigned long long comb = ((unsigned long long)a << 32) | b;
  uint r = 0;
#pragma unroll
  for (int i = 0; i < 4; ++i) {
    uint idx = (s >> (8 * i)) & 0xFF;
    uint by = (idx < 8) ? (uint)((comb >> (8 * idx)) & 0xFF) : 0u;
    r |= by << (8 * i);
  }
  return r;
}
#endif

// NF4 levels as f16 bit patterns (validated R10/R19: absmax 0.25).
#define TL0 0x52339200u
#define TL1 0x00D4EA8Du
#define TL2 0x68E02618u
#define TL3 0x00C9800Du
#define TH0 0xB6B8B9BCu
#define TH1 0x00ADB1B4u
#define TH2 0x3533312Du
#define TH3 0x3C393837u

__device__ __forceinline__ void deq4(uint s, uint sc2, uint& r0, uint& r1) {
  uint s7 = s & 0x07070707u;
  uint m = s & 0x08080808u;
  uint m8 = (m << 5) - (m >> 3);
  uint lo = (PERM(TL3, TL2, s7) & m8) | (PERM(TL1, TL0, s) & ~m8);
  uint hi = (PERM(TH3, TH2, s7) & m8) | (PERM(TH1, TH0, s) & ~m8);
  uint a0 = PERM(hi, lo, 0x05010400u);
  uint a1 = PERM(hi, lo, 0x07030602u);
  h2 v0 = __builtin_bit_cast(h2, a0) * __builtin_bit_cast(h2, sc2);
  h2 v1 = __builtin_bit_cast(h2, a1) * __builtin_bit_cast(h2, sc2);
  r0 = __builtin_bit_cast(uint, v0);
  r1 = __builtin_bit_cast(uint, v1);
}

// one packed dword (8 codes) -> 4 dwords (8 f16 in code order), scaled
__device__ __forceinline__ void deq8(uint d, uint sc2, uint* o) {
  uint e = d & 0x0F0F0F0Fu;
  uint od = (d >> 4) & 0x0F0F0F0Fu;
  uint sA = PERM(od, e, 0x05010400u);
  uint sB = PERM(od, e, 0x07030602u);
  deq4(sA, sc2, o[0], o[1]);
  deq4(sB, sc2, o[2], o[3]);
}

// ---------------- x f32 -> f16 ----------------
__global__ void cvt_f32_to_f16(const float* __restrict__ in,
                               _Float16* __restrict__ out, int total8) {
  int stride = gridDim.x * blockDim.x;
  for (int i = blockIdx.x * blockDim.x + threadIdx.x; i < total8; i += stride) {
    long e = (long)i * 8;
    const float4* ip = reinterpret_cast<const float4*>(in + e);
    float4 a = ip[0], b = ip[1];
    half8 o;
    o[0] = (_Float16)a.x; o[1] = (_Float16)a.y;
    o[2] = (_Float16)a.z; o[3] = (_Float16)a.w;
    o[4] = (_Float16)b.x; o[5] = (_Float16)b.y;
    o[6] = (_Float16)b.z; o[7] = (_Float16)b.w;
    *reinterpret_cast<half8*>(out + e) = o;
  }
}

// ---- NF4 dequant: codes[R,C] + scales[R,C/64] -> f16 [R][C] (down path) ----
__global__ void dequant_nf4(const int* __restrict__ codes,
                            const float* __restrict__ scales,
                            _Float16* __restrict__ out,
                            int total8, int C, int CB) {
  __shared__ float lut[16];
  if (threadIdx.x < 16) lut[threadIdx.x] = NF4_TAB[threadIdx.x];
  __syncthreads();
  int stride = gridDim.x * blockDim.x;
  for (int i = blockIdx.x * blockDim.x + threadIdx.x; i < total8; i += stride) {
    long e = (long)i * 8;
    int row = (int)(e / C);
    int col = (int)(e - (long)row * C);
    float sc = scales[row * CB + (col >> 6)];
    const int4* cp = reinterpret_cast<const int4*>(codes + e);
    int4 c0 = cp[0];
    int4 c1 = cp[1];
    half8 o;
    o[0] = (_Float16)(lut[c0.x & 15] * sc);
    o[1] = (_Float16)(lut[c0.y & 15] * sc);
    o[2] = (_Float16)(lut[c0.z & 15] * sc);
    o[3] = (_Float16)(lut[c0.w & 15] * sc);
    o[4] = (_Float16)(lut[c1.x & 15] * sc);
    o[5] = (_Float16)(lut[c1.y & 15] * sc);
    o[6] = (_Float16)(lut[c1.z & 15] * sc);
    o[7] = (_Float16)(lut[c1.w & 15] * sc);
    *reinterpret_cast<half8*>(out + e) = o;
  }
}

// ---- pack codes: int32 [R][C] -> nibbles [C/64][R][32B] ----
__global__ void pack_nf4(const int* __restrict__ codes,
                         unsigned char* __restrict__ pk, int R, int C) {
  const int CT = C >> 4;
  const long total = (long)R * CT;
  const long stride = (long)gridDim.x * blockDim.x;
  for (long i = blockIdx.x * blockDim.x + threadIdx.x; i < total; i += stride) {
    int r = (int)(i / CT);
    int g = (int)(i - (long)r * CT);
    int c0 = g << 4;
    const int4* p = reinterpret_cast<const int4*>(codes + (long)r * C + c0);
    int4 a = p[0], b = p[1], c = p[2], d = p[3];
    uint w0 = (uint)(a.x & 15) | ((uint)(a.y & 15) << 4) |
              ((uint)(a.z & 15) << 8) | ((uint)(a.w & 15) << 12) |
              ((uint)(b.x & 15) << 16) | ((uint)(b.y & 15) << 20) |
              ((uint)(b.z & 15) << 24) | ((uint)(b.w & 15) << 28);
    uint w1 = (uint)(c.x & 15) | ((uint)(c.y & 15) << 4) |
              ((uint)(c.z & 15) << 8) | ((uint)(c.w & 15) << 12) |
              ((uint)(d.x & 15) << 16) | ((uint)(d.y & 15) << 20) |
              ((uint)(d.z & 15) << 24) | ((uint)(d.w & 15) << 28);
    int kt = c0 >> 6;
    long off = ((long)kt * R + r) * 32 + ((c0 & 63) >> 1);
    uint2 v; v.x = w0; v.y = w1;
    *reinterpret_cast<uint2*>(pk + off) = v;
  }
}

// ---- pack scales: [R][CB] f32 -> [CB][R] f32 ----
__global__ void pack_scales(const float* __restrict__ s,
                            float* __restrict__ o, int R, int CB) {
  const long total = (long)R * CB;
  const long stride = (long)gridDim.x * blockDim.x;
  for (long i = blockIdx.x * blockDim.x + threadIdx.x; i < total; i += stride) {
    int r = (int)(i / CB);
    int cb = (int)(i - (long)r * CB);
    o[(long)cb * R + r] = s[i];
  }
}

// =====================================================================
// FUSED gate+up GEMM with IN-KERNEL NF4 B-DEQUANT (R19 skeleton; R20
// fixes the two measured defects):
// (1) CONFLICT-FREE ds_writes: R19's write put `q>>1` in the k-half
//     ADDRESS bit, so each instruction's 4 lanes/row covered only
//     chunks {0^wh,2^wh} -> 16/32 banks -> SQ_LDS_BANK_CONFLICT 4.5e7.
//     Fix: per-lane issue order s=q>>1 — instr A writes logical chunk
//     2(q&1)+s, instr B writes 2(q&1)+(1-s). Per 8-lane group each
//     instruction now covers chunks {0,1,2,3}^wh on both rows = all 32
//     banks exactly once.
// (2) SPLIT dequant: G at P2 (lgkmcnt(0) publish at P2-end; readers at
//     P0(t+1), 2 barriers later), U at P3 (publish P3-end; readers
//     P1(t+1)) — ~70 VALU/phase instead of 140 in P2.
// Ledger (unchanged from R19, re-walked for the split):
//   P0: reg loads [pkg,pku,scg,scu] then A0 gloads x2 (6 issues)
//   P1 vmcnt(6): certifies A@k1(t) [6 newer from P0]
//   P2: A1 gloads x2; G-dequant (compiler vmcnt(5) for pkg/scg — both
//       A pairs stay in flight); lgkmcnt(0) at end
//   P3: U-dequant (compiler vmcnt(4) for pku/scu); explicit vmcnt(2)
//       certifies A@k0(t+1) [A1 pair newer]; lgkmcnt(0) at end
//   Tail kt=NT-1: P1 vmcnt(0); no staging/dequant.
// WAR: sbuf G slab last read P0/P2(t-1) < write P2(t) (>=2 barriers);
//      U slab last read P1/P3(t-1) < write P3(t) (>=2 barriers).
// Rect XCD walk; chunk-XOR swizzle on A and B (read side proven 0-confl).
// =====================================================================
template <int K, int LD, int N>
__global__ __launch_bounds__(512, 2) void gemm_fused(
    const _Float16* __restrict__ A,
    const unsigned char* __restrict__ PKG,
    const unsigned char* __restrict__ PKU,
    const float* __restrict__ SCG,
    const float* __restrict__ SCU,
    _Float16* __restrict__ GH) {
  constexpr int NT = K / 64;
  __shared__ __align__(16) _Float16 lds[2 * 32768];  // 128 KB

  const int t = threadIdx.x;       // 0..511
  const int lane = t & 63;
  const int wave = t >> 6;
  const int wm = wave >> 2;        // 0..1
  const int wn = wave & 3;         // 0..3

  const int xcd = blockIdx.x & 7;
  const int j = blockIdx.x >> 3;
  const int bm = 4 * xcd + (j & 3);
  const int bn = j >> 2;           // 0..N/128-1

  // ---- A staging (linear LDS dest, pre-permuted global src) ----
  const int lc = (t & 3) ^ ((t >> 3) & 3);
  const _Float16* gA = A + ((long)bm * 256 + (t >> 2)) * LD + lc * 8;
  const long rstep = (long)128 * LD;
  const int dst = t * 8;

  // ---- B packed addressing: row r = t>>2 (0..127), quarter q = t&3 ----
  const int r = t >> 2;
  const int q = t & 3;
  const int s = q >> 1;            // k-half AND write-order selector
  const int wh = (r >> 1) & 3;     // h(row) for chunk swizzle
  const unsigned char* gPKG = PKG + ((long)(bn * 128 + r)) * 32 + q * 8;
  const unsigned char* gPKU = PKU + ((long)(bn * 128 + r)) * 32 + q * 8;
  const float* gSCG = SCG + (bn * 128 + r);
  const float* gSCU = SCU + (bn * 128 + r);
  const long pkstep = (long)N * 32;

  // write offsets (f16 units within slab): instr A -> chunk 2(q&1)+s,
  // instr B -> chunk 2(q&1)+(1-s); physical = logical ^ wh.
  const int wbase = s * 4096 + r * 32;  // k-half s, row r
  const int offWA = wbase + (((2 * (q & 1) + s) ^ wh) * 8);
  const int offWB = wbase + (((2 * (q & 1) + (1 - s)) ^ wh) * 8);

  // ---- fragment read offsets ----
  const int rA = wm * 128 + (lane & 15);
  const int rB = wn * 32 + (lane & 15);
  const int ckA = ((lane >> 4) ^ ((rA >> 1) & 3)) * 8;
  const int ckB = ((lane >> 4) ^ ((rB >> 1) & 3)) * 8;
  const int offA = rA * 32 + ckA;            // + i*512 (+8192 for k1)
  const int offBG = 16384 + rB * 32 + ckB;   // + j2*512 (+4096 for k1)
  const int offBU = 24576 + rB * 32 + ckB;

  uint2 pkg, pku;
  float scg, scu;

  // dequant G regs -> G slab of buffer db (conflict-free swapped writes)
  auto stage_g = [&](int db) {
    _Float16 sh = (_Float16)scg;
    unsigned short us = __builtin_bit_cast(unsigned short, sh);
    uint sc2 = (uint)us * 0x10001u;
    uint o0[4], o1[4];
    deq8(pkg.x, sc2, o0);   // logical chunk 2(q&1)
    deq8(pkg.y, sc2, o1);   // logical chunk 2(q&1)+1
    uint4 v0; v0.x = o0[0]; v0.y = o0[1]; v0.z = o0[2]; v0.w = o0[3];
    uint4 v1; v1.x = o1[0]; v1.y = o1[1]; v1.z = o1[2]; v1.w = o1[3];
    _Float16* base = lds + db * 32768 + 16384;
    *reinterpret_cast<uint4*>(base + offWA) = s ? v1 : v0;
    *reinterpret_cast<uint4*>(base + offWB) = s ? v0 : v1;
  };
  auto stage_u = [&](int db) {
    _Float16 sh = (_Float16)scu;
    unsigned short us = __builtin_bit_cast(unsigned short, sh);
    uint sc2 = (uint)us * 0x10001u;
    uint o0[4], o1[4];
    deq8(pku.x, sc2, o0);
    deq8(pku.y, sc2, o1);
    uint4 v0; v0.x = o0[0]; v0.y = o0[1]; v0.z = o0[2]; v0.w = o0[3];
    uint4 v1; v1.x = o1[0]; v1.y = o1[1]; v1.z = o1[2]; v1.w = o1[3];
    _Float16* base = lds + db * 32768 + 24576;
    *reinterpret_cast<uint4*>(base + offWA) = s ? v1 : v0;
    *reinterpret_cast<uint4*>(base + offWB) = s ? v0 : v1;
  };

  // ---- prologue: tile 0 ----
  pkg = *reinterpret_cast<const uint2*>(gPKG);
  pku = *reinterpret_cast<const uint2*>(gPKU);
  scg = *gSCG;
  scu = *gSCU;
  gPKG += pkstep; gPKU += pkstep; gSCG += N; gSCU += N;
  FENCE();
  gload16(gA, lds + dst);
  gload16(gA + rstep, lds + dst + 4096);
  gload16(gA + 32, lds + 8192 + dst);
  gload16(gA + 32 + rstep, lds + 8192 + dst + 4096);
  gA += 64;
  FENCE();
  stage_g(0);
  stage_u(0);                                        // compiler: vmcnt(4)
  asm volatile("s_waitcnt vmcnt(2)" ::: "memory");   // A@k0(0) done; A1 flying
  asm volatile("s_waitcnt lgkmcnt(0)" ::: "memory");
  __builtin_amdgcn_s_barrier();
  FENCE();

  floatx4 accG[8][2] = {};
  floatx4 accU[8][2] = {};

  for (int kt = 0; kt < NT; ++kt) {
    const int cb = kt & 1;
    const int sbuf = cb ^ 1;
    const _Float16* lb = lds + cb * 32768;
    _Float16* sb = lds + sbuf * 32768;
    const bool st = (kt + 1 < NT);
    const bool last = (kt == NT - 1);

    half8 a[8], b[2];

    // ---- P0: read a@k0 x8 + bg@k0 x2; load regs(t+1); stage A0(t+1) ----
#pragma unroll
    for (int i = 0; i < 8; ++i)
      a[i] = *reinterpret_cast<const half8*>(&lb[offA + i * 512]);
    b[0] = *reinterpret_cast<const half8*>(&lb[offBG]);
    b[1] = *reinterpret_cast<const half8*>(&lb[offBG + 512]);
    if (st) {
      pkg = *reinterpret_cast<const uint2*>(gPKG);
      pku = *reinterpret_cast<const uint2*>(gPKU);
      scg = *gSCG;
      scu = *gSCU;
      gPKG += pkstep; gPKU += pkstep; gSCG += N; gSCU += N;
      FENCE();
      gload16(gA, sb + dst);
      gload16(gA + rstep, sb + dst + 4096);
    }
    __builtin_amdgcn_s_barrier();
    FENCE();
    __builtin_amdgcn_s_setprio(1);
#pragma unroll
    for (int i = 0; i < 8; ++i) {
      accG[i][0] = __builtin_amdgcn_mfma_f32_16x16x32_f16(a[i], b[0], accG[i][0], 0, 0, 0);
      accG[i][1] = __builtin_amdgcn_mfma_f32_16x16x32_f16(a[i], b[1], accG[i][1], 0, 0, 0);
    }
    __builtin_amdgcn_s_setprio(0);
    __builtin_amdgcn_s_barrier();
    FENCE();

    // ---- P1: read bu@k0 x2 (a held); certify A@k1(t) ----
    b[0] = *reinterpret_cast<const half8*>(&lb[offBU]);
    b[1] = *reinterpret_cast<const half8*>(&lb[offBU + 512]);
    if (last) { asm volatile("s_waitcnt vmcnt(0)" ::: "memory"); }
    else      { asm volatile("s_waitcnt vmcnt(6)" ::: "memory"); }
    __builtin_amdgcn_s_barrier();
    FENCE();
    __builtin_amdgcn_s_setprio(1);
#pragma unroll
    for (int i = 0; i < 8; ++i) {
      accU[i][0] = __builtin_amdgcn_mfma_f32_16x16x32_f16(a[i], b[0], accU[i][0], 0, 0, 0);
      accU[i][1] = __builtin_amdgcn_mfma_f32_16x16x32_f16(a[i], b[1], accU[i][1], 0, 0, 0);
    }
    __builtin_amdgcn_s_setprio(0);
    __builtin_amdgcn_s_barrier();
    FENCE();

    // ---- P2: read a@k1 x8 + bg@k1 x2; stage A1(t+1); dequant G(t+1) ----
#pragma unroll
    for (int i = 0; i < 8; ++i)
      a[i] = *reinterpret_cast<const half8*>(&lb[8192 + offA + i * 512]);
    b[0] = *reinterpret_cast<const half8*>(&lb[offBG + 4096]);
    b[1] = *reinterpret_cast<const half8*>(&lb[offBG + 4096 + 512]);
    if (st) {
      gload16(gA + 32, sb + 8192 + dst);
      gload16(gA + 32 + rstep, sb + 8192 + dst + 4096);
      gA += 64;
      FENCE();
      stage_g(sbuf);  // compiler vmcnt(5) for pkg/scg; A pairs in flight
    }
    __builtin_amdgcn_s_barrier();
    FENCE();
    __builtin_amdgcn_s_setprio(1);
#pragma unroll
    for (int i = 0; i < 8; ++i) {
      accG[i][0] = __builtin_amdgcn_mfma_f32_16x16x32_f16(a[i], b[0], accG[i][0], 0, 0, 0);
      accG[i][1] = __builtin_amdgcn_mfma_f32_16x16x32_f16(a[i], b[1], accG[i][1], 0, 0, 0);
    }
    __builtin_amdgcn_s_setprio(0);
    asm volatile("s_waitcnt lgkmcnt(0)" ::: "memory");  // publish G writes
    __builtin_amdgcn_s_barrier();
    FENCE();

    // ---- P3: read bu@k1 x2 (a held); dequant U(t+1); cert A@k0(t+1) ----
    b[0] = *reinterpret_cast<const half8*>(&lb[offBU + 4096]);
    b[1] = *reinterpret_cast<const half8*>(&lb[offBU + 4096 + 512]);
    if (st) {
      stage_u(sbuf);  // compiler vmcnt(4) for pku/scu; A pairs in flight
    }
    if (st) { asm volatile("s_waitcnt vmcnt(2)" ::: "memory"); }
    __builtin_amdgcn_s_barrier();
    FENCE();
    __builtin_amdgcn_s_setprio(1);
#pragma unroll
    for (int i = 0; i < 8; ++i) {
      accU[i][0] = __builtin_amdgcn_mfma_f32_16x16x32_f16(a[i], b[0], accU[i][0], 0, 0, 0);
      accU[i][1] = __builtin_amdgcn_mfma_f32_16x16x32_f16(a[i], b[1], accU[i][1], 0, 0, 0);
    }
    __builtin_amdgcn_s_setprio(0);
    asm volatile("s_waitcnt lgkmcnt(0)" ::: "memory");  // publish U writes
    __builtin_amdgcn_s_barrier();
    FENCE();
  }

  // ---- epilogue: h = silu(g)*u in registers, single f16 store ----
  const int r0 = bm * 256 + wm * 128 + (lane >> 4) * 4;
  const int c0 = bn * 128 + wn * 32 + (lane & 15);
#pragma unroll
  for (int i = 0; i < 8; ++i) {
#pragma unroll
    for (int j2 = 0; j2 < 2; ++j2) {
#pragma unroll
      for (int ii = 0; ii < 4; ++ii) {
        const long idx = (long)(r0 + i * 16 + ii) * N + (c0 + j2 * 16);
        float g = accG[i][j2][ii];
        float u = accU[i][j2][ii];
        GH[idx] = (_Float16)(g / (1.0f + __expf(-g)) * u);
      }
    }
  }
}

// =====================================================================
// gemm256: banked R13 256x256 kernel (validated), used for down-GEMM.
// =====================================================================
template <int K, int LD, int N, int EPI>
__global__ __launch_bounds__(512, 2) void gemm256(
    const _Float16* __restrict__ A,
    const _Float16* __restrict__ B,
    _Float16* __restrict__ GH,
    float* __restrict__ OUT) {
  constexpr int NT = K / 64;
  constexpr int NBC = N / 256;
  __shared__ __align__(16) _Float16 lds[2 * 32768];  // 128 KB

  const int t = threadIdx.x;
  const int lane = t & 63;
  const int wave = t >> 6;
  const int wm = wave >> 2;
  const int wn = wave & 3;

  const int xcd = blockIdx.x & 7;
  const int j = blockIdx.x >> 3;
  const int bm = 4 * xcd + (j & 3);
  const int bn = j >> 2;

  const int lc = (t & 3) ^ ((t >> 3) & 3);
  const _Float16* gA = A + ((long)bm * 256 + (t >> 2)) * LD + lc * 8;
  const _Float16* gB = B + ((long)bn * 256 + (t >> 2)) * LD + lc * 8;
  const long rstep = (long)128 * LD;
  const int dst = t * 8;

  const int rA = wm * 128 + (lane & 15);
  const int rB = wn * 64 + (lane & 15);
  const int ckA = ((lane >> 4) ^ ((rA >> 1) & 3)) * 8;
  const int ckB = ((lane >> 4) ^ ((rB >> 1) & 3)) * 8;
  const int offA = rA * 32 + ckA;
  const int offB = 16384 + rB * 32 + ckB;

#define STAGE_SLOT(gp, slab, koff, dbuf)                                   \
  gload16((gp) + (koff), lds + (dbuf) * 32768 + (slab) + dst);             \
  gload16((gp) + (koff) + rstep, lds + (dbuf) * 32768 + (slab) + dst + 4096);

  STAGE_SLOT(gA, 0, 0, 0);
  STAGE_SLOT(gB, 16384, 0, 0);
  STAGE_SLOT(gA, 8192, 32, 0);
  STAGE_SLOT(gB, 24576, 32, 0);
  gA += 64; gB += 64;
  asm volatile("s_waitcnt vmcnt(4)" ::: "memory");
  __builtin_amdgcn_s_barrier();
  FENCE();

  floatx4 acc[8][4] = {};

  for (int kt = 0; kt < NT; ++kt) {
    const int cb = kt & 1;
    const int sbuf = cb ^ 1;
    const _Float16* lb = lds + cb * 32768;
    const bool st = (kt + 1 < NT);
    const bool last = (kt == NT - 1);

    half8 a[8], b[2];

#pragma unroll
    for (int i = 0; i < 8; ++i)
      a[i] = *reinterpret_cast<const half8*>(&lb[offA + i * 512]);
    b[0] = *reinterpret_cast<const half8*>(&lb[offB]);
    b[1] = *reinterpret_cast<const half8*>(&lb[offB + 512]);
    if (st) { STAGE_SLOT(gA, 0, 0, sbuf); }
    __builtin_amdgcn_s_barrier();
    FENCE();
    __builtin_amdgcn_s_setprio(1);
#pragma unroll
    for (int i = 0; i < 8; ++i) {
      acc[i][0] = __builtin_amdgcn_mfma_f32_16x16x32_f16(a[i], b[0], acc[i][0], 0, 0, 0);
      acc[i][1] = __builtin_amdgcn_mfma_f32_16x16x32_f16(a[i], b[1], acc[i][1], 0, 0, 0);
    }
    __builtin_amdgcn_s_setprio(0);
    __builtin_amdgcn_s_barrier();
    FENCE();

    b[0] = *reinterpret_cast<const half8*>(&lb[offB + 2 * 512]);
    b[1] = *reinterpret_cast<const half8*>(&lb[offB + 3 * 512]);
    if (st) { STAGE_SLOT(gB, 16384, 0, sbuf); }
    if (last) { asm volatile("s_waitcnt vmcnt(0)" ::: "memory"); }
    else      { asm volatile("s_waitcnt vmcnt(4)" ::: "memory"); }
    __builtin_amdgcn_s_barrier();
    FENCE();
    __builtin_amdgcn_s_setprio(1);
#pragma unroll
    for (int i = 0; i < 8; ++i) {
      acc[i][2] = __builtin_amdgcn_mfma_f32_16x16x32_f16(a[i], b[0], acc[i][2], 0, 0, 0);
      acc[i][3] = __builtin_amdgcn_mfma_f32_16x16x32_f16(a[i], b[1], acc[i][3], 0, 0, 0);
    }
    __builtin_amdgcn_s_setprio(0);
    __builtin_amdgcn_s_barrier();
    FENCE();

#pragma unroll
    for (int i = 0; i < 8; ++i)
      a[i] = *reinterpret_cast<const half8*>(&lb[8192 + offA + i * 512]);
    b[0] = *reinterpret_cast<const half8*>(&lb[8192 + offB]);
    b[1] = *reinterpret_cast<const half8*>(&lb[8192 + offB + 512]);
    if (st) { STAGE_SLOT(gA, 8192, 32, sbuf); }
    __builtin_amdgcn_s_barrier();
    FENCE();
    __builtin_amdgcn_s_setprio(1);
#pragma unroll
    for (int i = 0; i < 8; ++i) {
      acc[i][0] = __builtin_amdgcn_mfma_f32_16x16x32_f16(a[i], b[0], acc[i][0], 0, 0, 0);
      acc[i][1] = __builtin_amdgcn_mfma_f32_16x16x32_f16(a[i], b[1], acc[i][1], 0, 0, 0);
    }
    __builtin_amdgcn_s_setprio(0);
    __builtin_amdgcn_s_barrier();
    FENCE();

    b[0] = *reinterpret_cast<const half8*>(&lb[8192 + offB + 2 * 512]);
    b[1] = *reinterpret_cast<const half8*>(&lb[8192 + offB + 3 * 512]);
    if (st) { STAGE_SLOT(gB, 24576, 32, sbuf); gA += 64; gB += 64; }
    if (!last) { asm volatile("s_waitcnt vmcnt(4)" ::: "memory"); }
    __builtin_amdgcn_s_barrier();
    FENCE();
    __builtin_amdgcn_s_setprio(1);
#pragma unroll
    for (int i = 0; i < 8; ++i) {
      acc[i][2] = __builtin_amdgcn_mfma_f32_16x16x32_f16(a[i], b[0], acc[i][2], 0, 0, 0);
      acc[i][3] = __builtin_amdgcn_mfma_f32_16x16x32_f16(a[i], b[1], acc[i][3], 0, 0, 0);
    }
    __builtin_amdgcn_s_setprio(0);
    __builtin_amdgcn_s_barrier();
    FENCE();
  }
#undef STAGE_SLOT

  const int r0 = bm * 256 + wm * 128 + (lane >> 4) * 4;
  const int c0 = bn * 256 + wn * 64 + (lane & 15);
#pragma unroll
  for (int i = 0; i < 8; ++i) {
#pragma unroll
    for (int j2 = 0; j2 < 4; ++j2) {
#pragma unroll
      for (int ii = 0; ii < 4; ++ii) {
        const long idx = (long)(r0 + i * 16 + ii) * N + (c0 + j2 * 16);
        if (EPI == 0) {
          GH[idx] = (_Float16)acc[i][j2][ii];
        } else {
          OUT[idx] = acc[i][j2][ii];
        }
      }
    }
  }
}

extern "C" void kernel_launch(void* const* d_in, const int* in_sizes, int n_in,
                              void* d_out, int out_size, void* d_ws, size_t ws_size,
                              hipStream_t stream) {
  const float* x           = (const float*)d_in[0];
  const int*   gate_codes  = (const int*)d_in[1];
  const float* gate_scales = (const float*)d_in[2];
  const int*   up_codes    = (const int*)d_in[3];
  const float* up_scales   = (const float*)d_in[4];
  const int*   down_codes  = (const int*)d_in[5];
  const float* down_scales = (const float*)d_in[6];
  float* out = (float*)d_out;

  const long T = 8192, HD = 4096, M = 11008;

  // ws: x16 67MB | pkG 22.5 | pkU 22.5 | scG 2.8 | scU 2.8 | Wd 90 | gh 180
  char* ws = (char*)d_ws;
  _Float16* x16 = (_Float16*)ws;                   ws += T * HD * 2;
  unsigned char* pkG = (unsigned char*)ws;         ws += M * HD / 2;
  unsigned char* pkU = (unsigned char*)ws;         ws += M * HD / 2;
  float* scG = (float*)ws;                         ws += (HD / 64) * M * 4;
  float* scU = (float*)ws;                         ws += (HD / 64) * M * 4;
  _Float16* Wd = (_Float16*)ws;                    ws += HD * M * 2;
  _Float16* gh = (_Float16*)ws;

  cvt_f32_to_f16<<<2048, 256, 0, stream>>>(x, x16, (int)(T * HD / 8));
  pack_nf4<<<2048, 256, 0, stream>>>(gate_codes, pkG, (int)M, (int)HD);
  pack_nf4<<<2048, 256, 0, stream>>>(up_codes, pkU, (int)M, (int)HD);
  pack_scales<<<2048, 256, 0, stream>>>(gate_scales, scG, (int)M, (int)(HD / 64));
  pack_scales<<<2048, 256, 0, stream>>>(up_scales, scU, (int)M, (int)(HD / 64));

  // fused gate+up+SwiGLU: gh = silu(x@Wg^T) * (x@Wu^T)  (in-kernel dequant)
  gemm_fused<4096, 4096, 11008><<<(8192 / 256) * (11008 / 128), 512, 0, stream>>>(
      x16, pkG, pkU, scG, scU, gh);

  // down: out = gh @ Wd^T (f32)
  dequant_nf4<<<2048, 256, 0, stream>>>(down_codes, down_scales, Wd,
                                        (int)(HD * M / 8), (int)M, (int)(M / 64));
  gemm256<11008, 11008, 4096, 2><<<(8192 / 256) * (4096 / 256), 512, 0, stream>>>(
      gh, Wd, nullptr, out);
}

// Round 21
// 2119.680 us; speedup vs baseline: 1.6639x; 1.6639x over previous
//
#include <hip/hip_runtime.h>
#include <hip/hip_bf16.h>

typedef _Float16 half8 __attribute__((ext_vector_type(8)));
typedef float floatx4 __attribute__((ext_vector_type(4)));

__device__ __constant__ float NF4_TAB[16] = {
    -1.0f, -0.6961928009986877f, -0.5250730514526367f, -0.39491748809814453f,
    -0.28444138169288635f, -0.18477343022823334f, -0.09105003625154495f, 0.0f,
    0.07958029955625534f, 0.16093020141124725f, 0.24611230194568634f,
    0.33791524171829224f, 0.44070982933044434f, 0.5626170039176941f,
    0.7229568362236023f, 1.0f};

typedef __attribute__((address_space(3))) void lds_t;
typedef __attribute__((address_space(1))) void gbl_t;

__device__ __forceinline__ void gload16(const void* g, void* l) {
  __builtin_amdgcn_global_load_lds((gbl_t*)g, (lds_t*)l, 16, 0, 0);
}

#define FENCE() asm volatile("" ::: "memory")

// ---------------- x f32 -> f16 (row stride OS) ----------------
__global__ void cvt_f32_to_f16_pad(const float* __restrict__ in,
                                   _Float16* __restrict__ out,
                                   int total8, int C8, int OS) {
  int stride = gridDim.x * blockDim.x;
  for (int i = blockIdx.x * blockDim.x + threadIdx.x; i < total8; i += stride) {
    int row = i / C8;
    int col = (i - row * C8) * 8;
    const float4* ip = reinterpret_cast<const float4*>(in + (long)row * (C8 * 8) + col);
    float4 a = ip[0], b = ip[1];
    half8 o;
    o[0] = (_Float16)a.x; o[1] = (_Float16)a.y;
    o[2] = (_Float16)a.z; o[3] = (_Float16)a.w;
    o[4] = (_Float16)b.x; o[5] = (_Float16)b.y;
    o[6] = (_Float16)b.z; o[7] = (_Float16)b.w;
    *reinterpret_cast<half8*>(out + (long)row * OS + col) = o;
  }
}

// ---- NF4 dequant: codes[R,C] + scales[R,C/64] -> f16 [R][OS-strided] ----
__global__ void dequant_nf4(const int* __restrict__ codes,
                            const float* __restrict__ scales,
                            _Float16* __restrict__ out,
                            int total8, int C, int CB, int OS) {
  __shared__ float lut[16];
  if (threadIdx.x < 16) lut[threadIdx.x] = NF4_TAB[threadIdx.x];
  __syncthreads();
  int stride = gridDim.x * blockDim.x;
  for (int i = blockIdx.x * blockDim.x + threadIdx.x; i < total8; i += stride) {
    long e = (long)i * 8;
    int row = (int)(e / C);
    int col = (int)(e - (long)row * C);
    float sc = scales[row * CB + (col >> 6)];
    const int4* cp = reinterpret_cast<const int4*>(codes + e);
    int4 c0 = cp[0];
    int4 c1 = cp[1];
    half8 o;
    o[0] = (_Float16)(lut[c0.x & 15] * sc);
    o[1] = (_Float16)(lut[c0.y & 15] * sc);
    o[2] = (_Float16)(lut[c0.z & 15] * sc);
    o[3] = (_Float16)(lut[c0.w & 15] * sc);
    o[4] = (_Float16)(lut[c1.x & 15] * sc);
    o[5] = (_Float16)(lut[c1.y & 15] * sc);
    o[6] = (_Float16)(lut[c1.z & 15] * sc);
    o[7] = (_Float16)(lut[c1.w & 15] * sc);
    *reinterpret_cast<half8*>(out + (long)row * OS + col) = o;
  }
}

// =====================================================================
// FUSED gate+up GEMM (BANKED R18, validated: fused ~1400us @ 50.5%
// MfmaUtil, 0 bank conflicts, graph-replay clean). 256(M) x 128(N per
// matrix) tile, BK=64, 8 waves (2Mx4N); computes
//   gh = silu(x@Wg^T) * (x@Wu^T) in one pass (no gh round-trip).
// R7-lineage staging/ledger (validated 5x): 4 phases/K-tile, one stage
// slot (2 gloads) per phase: P0->A0, P1->(Gk0,Uk0), P2->A1, P3->(Gk1,Uk1);
// counted vmcnt(4) at P1 (certifies A1,Gk1,Uk1(t)) and P3 (certifies
// A0,Gk0,Uk0(t+1)); never 0 mid-loop; tail P1(NT-1) vmcnt(0).
// WAR: every sbuf slab overwrite >=4 barriers after its last read.
// LDS per 64KB buffer (f16 units): A@k0=0, A@k1=8192,
//   G@k0=16384, G@k1=20480, U@k0=24576, U@k1=28672.
// Chunk-XOR swizzle (phys chunk = logical ^ ((row>>1)&3)): 0 conflicts.
// Rect XCD walk: xcd=bid&7, bm=4*xcd+(j&3), bn=j>>2 (bijective, NBM=32).
// POST-MORTEM NOTE (R19/R20): in-kernel NF4 B-dequant reduced FETCH 36%
// as predicted but never beat this kernel — R19 lost to ds_write bank
// conflicts (4.5e7), R20's conflict-free/split variant lost to schedule
// restructuring (MfmaUtil 50->21, WRITE_SIZE +70MB). Line closed.
// =====================================================================
template <int K, int LD, int N>
__global__ __launch_bounds__(512, 2) void gemm_fused(
    const _Float16* __restrict__ A,
    const _Float16* __restrict__ G,
    const _Float16* __restrict__ U,
    _Float16* __restrict__ GH) {
  constexpr int NT = K / 64;
  __shared__ __align__(16) _Float16 lds[2 * 32768];  // 128 KB

  const int t = threadIdx.x;       // 0..511
  const int lane = t & 63;
  const int wave = t >> 6;
  const int wm = wave >> 2;        // 0..1
  const int wn = wave & 3;         // 0..3

  const int xcd = blockIdx.x & 7;
  const int j = blockIdx.x >> 3;
  const int bm = 4 * xcd + (j & 3);
  const int bn = j >> 2;           // 0..85

  // staging (linear LDS dest, pre-permuted global src)
  const int lc = (t & 3) ^ ((t >> 3) & 3);
  const _Float16* gA = A + ((long)bm * 256 + (t >> 2)) * LD + lc * 8;
  const _Float16* gG = G + ((long)bn * 128 + (t >> 2)) * LD + lc * 8;
  const _Float16* gU = U + ((long)bn * 128 + (t >> 2)) * LD + lc * 8;
  const long rstep = (long)128 * LD;
  const int dst = t * 8;  // f16 units

  // fragment read offsets
  const int rA = wm * 128 + (lane & 15);
  const int rB = wn * 32 + (lane & 15);
  const int ckA = ((lane >> 4) ^ ((rA >> 1) & 3)) * 8;  // h(r+16i)==h(r)
  const int ckB = ((lane >> 4) ^ ((rB >> 1) & 3)) * 8;
  const int offA = rA * 32 + ckA;            // + i*512 (+8192 for k1)
  const int offBG = 16384 + rB * 32 + ckB;   // + j2*512 (+4096 for k1)
  const int offBU = 24576 + rB * 32 + ckB;   // + j2*512 (+4096 for k1)

  // ---- prologue: stage tile 0 -> buf0 in slot order A0,(Gk0,Uk0),A1,(Gk1,Uk1)
  gload16(gA, lds + dst);
  gload16(gA + rstep, lds + dst + 4096);
  gload16(gG, lds + 16384 + dst);
  gload16(gU, lds + 24576 + dst);
  gload16(gA + 32, lds + 8192 + dst);
  gload16(gA + 32 + rstep, lds + 8192 + dst + 4096);
  gload16(gG + 32, lds + 20480 + dst);
  gload16(gU + 32, lds + 28672 + dst);
  gA += 64; gG += 64; gU += 64;
  asm volatile("s_waitcnt vmcnt(4)" ::: "memory");  // A0,Gk0,Uk0(0) done
  __builtin_amdgcn_s_barrier();
  FENCE();

  floatx4 accG[8][2] = {};
  floatx4 accU[8][2] = {};

  for (int kt = 0; kt < NT; ++kt) {
    const int cb = kt & 1;
    const int sbuf = cb ^ 1;
    const _Float16* lb = lds + cb * 32768;
    _Float16* sb = lds + sbuf * 32768;
    const bool st = (kt + 1 < NT);
    const bool last = (kt == NT - 1);

    half8 a[8], b[2];

    // ---- P0: read a@k0 x8 + bg@k0 x2; stage A0(t+1); accG ----
#pragma unroll
    for (int i = 0; i < 8; ++i)
      a[i] = *reinterpret_cast<const half8*>(&lb[offA + i * 512]);
    b[0] = *reinterpret_cast<const half8*>(&lb[offBG]);
    b[1] = *reinterpret_cast<const half8*>(&lb[offBG + 512]);
    if (st) { gload16(gA, sb + dst); gload16(gA + rstep, sb + dst + 4096); }
    __builtin_amdgcn_s_barrier();
    FENCE();
    __builtin_amdgcn_s_setprio(1);
#pragma unroll
    for (int i = 0; i < 8; ++i) {
      accG[i][0] = __builtin_amdgcn_mfma_f32_16x16x32_f16(a[i], b[0], accG[i][0], 0, 0, 0);
      accG[i][1] = __builtin_amdgcn_mfma_f32_16x16x32_f16(a[i], b[1], accG[i][1], 0, 0, 0);
    }
    __builtin_amdgcn_s_setprio(0);
    __builtin_amdgcn_s_barrier();
    FENCE();

    // ---- P1: read bu@k0 x2 (a held); stage Gk0,Uk0(t+1); cert A1,Gk1,Uk1(t) ----
    b[0] = *reinterpret_cast<const half8*>(&lb[offBU]);
    b[1] = *reinterpret_cast<const half8*>(&lb[offBU + 512]);
    if (st) { gload16(gG, sb + 16384 + dst); gload16(gU, sb + 24576 + dst); }
    if (last) { asm volatile("s_waitcnt vmcnt(0)" ::: "memory"); }
    else      { asm volatile("s_waitcnt vmcnt(4)" ::: "memory"); }
    __builtin_amdgcn_s_barrier();
    FENCE();
    __builtin_amdgcn_s_setprio(1);
#pragma unroll
    for (int i = 0; i < 8; ++i) {
      accU[i][0] = __builtin_amdgcn_mfma_f32_16x16x32_f16(a[i], b[0], accU[i][0], 0, 0, 0);
      accU[i][1] = __builtin_amdgcn_mfma_f32_16x16x32_f16(a[i], b[1], accU[i][1], 0, 0, 0);
    }
    __builtin_amdgcn_s_setprio(0);
    __builtin_amdgcn_s_barrier();
    FENCE();

    // ---- P2: read a@k1 x8 + bg@k1 x2; stage A1(t+1); accG ----
#pragma unroll
    for (int i = 0; i < 8; ++i)
      a[i] = *reinterpret_cast<const half8*>(&lb[8192 + offA + i * 512]);
    b[0] = *reinterpret_cast<const half8*>(&lb[offBG + 4096]);
    b[1] = *reinterpret_cast<const half8*>(&lb[offBG + 4096 + 512]);
    if (st) { gload16(gA + 32, sb + 8192 + dst); gload16(gA + 32 + rstep, sb + 8192 + dst + 4096); }
    __builtin_amdgcn_s_barrier();
    FENCE();
    __builtin_amdgcn_s_setprio(1);
#pragma unroll
    for (int i = 0; i < 8; ++i) {
      accG[i][0] = __builtin_amdgcn_mfma_f32_16x16x32_f16(a[i], b[0], accG[i][0], 0, 0, 0);
      accG[i][1] = __builtin_amdgcn_mfma_f32_16x16x32_f16(a[i], b[1], accG[i][1], 0, 0, 0);
    }
    __builtin_amdgcn_s_setprio(0);
    __builtin_amdgcn_s_barrier();
    FENCE();

    // ---- P3: read bu@k1 x2 (a held); stage Gk1,Uk1(t+1); cert A0,Gk0,Uk0(t+1) ----
    b[0] = *reinterpret_cast<const half8*>(&lb[offBU + 4096]);
    b[1] = *reinterpret_cast<const half8*>(&lb[offBU + 4096 + 512]);
    if (st) {
      gload16(gG + 32, sb + 20480 + dst);
      gload16(gU + 32, sb + 28672 + dst);
      gA += 64; gG += 64; gU += 64;
    }
    if (!last) { asm volatile("s_waitcnt vmcnt(4)" ::: "memory"); }
    __builtin_amdgcn_s_barrier();
    FENCE();
    __builtin_amdgcn_s_setprio(1);
#pragma unroll
    for (int i = 0; i < 8; ++i) {
      accU[i][0] = __builtin_amdgcn_mfma_f32_16x16x32_f16(a[i], b[0], accU[i][0], 0, 0, 0);
      accU[i][1] = __builtin_amdgcn_mfma_f32_16x16x32_f16(a[i], b[1], accU[i][1], 0, 0, 0);
    }
    __builtin_amdgcn_s_setprio(0);
    __builtin_amdgcn_s_barrier();
    FENCE();
  }

  // ---- epilogue: h = silu(g)*u in registers, single f16 store ----
  const int r0 = bm * 256 + wm * 128 + (lane >> 4) * 4;
  const int c0 = bn * 128 + wn * 32 + (lane & 15);
#pragma unroll
  for (int i = 0; i < 8; ++i) {
#pragma unroll
    for (int j2 = 0; j2 < 2; ++j2) {
#pragma unroll
      for (int ii = 0; ii < 4; ++ii) {
        const long idx = (long)(r0 + i * 16 + ii) * N + (c0 + j2 * 16);
        float g = accG[i][j2][ii];
        float u = accU[i][j2][ii];
        GH[idx] = (_Float16)(g / (1.0f + __expf(-g)) * u);
      }
    }
  }
}

// =====================================================================
// gemm256: banked R13 256x256 kernel (validated), used for down-GEMM.
// =====================================================================
template <int K, int LD, int N, int EPI>
__global__ __launch_bounds__(512, 2) void gemm256(
    const _Float16* __restrict__ A,
    const _Float16* __restrict__ B,
    _Float16* __restrict__ GH,
    float* __restrict__ OUT) {
  constexpr int NT = K / 64;
  constexpr int NBC = N / 256;
  __shared__ __align__(16) _Float16 lds[2 * 32768];  // 128 KB

  const int t = threadIdx.x;
  const int lane = t & 63;
  const int wave = t >> 6;
  const int wm = wave >> 2;
  const int wn = wave & 3;

  const int xcd = blockIdx.x & 7;
  const int j = blockIdx.x >> 3;
  const int bm = 4 * xcd + (j & 3);
  const int bn = j >> 2;

  const int lc = (t & 3) ^ ((t >> 3) & 3);
  const _Float16* gA = A + ((long)bm * 256 + (t >> 2)) * LD + lc * 8;
  const _Float16* gB = B + ((long)bn * 256 + (t >> 2)) * LD + lc * 8;
  const long rstep = (long)128 * LD;
  const int dst = t * 8;

  const int rA = wm * 128 + (lane & 15);
  const int rB = wn * 64 + (lane & 15);
  const int ckA = ((lane >> 4) ^ ((rA >> 1) & 3)) * 8;
  const int ckB = ((lane >> 4) ^ ((rB >> 1) & 3)) * 8;
  const int offA = rA * 32 + ckA;
  const int offB = 16384 + rB * 32 + ckB;

#define STAGE_SLOT(gp, slab, koff, dbuf)                                   \
  gload16((gp) + (koff), lds + (dbuf) * 32768 + (slab) + dst);             \
  gload16((gp) + (koff) + rstep, lds + (dbuf) * 32768 + (slab) + dst + 4096);

  STAGE_SLOT(gA, 0, 0, 0);
  STAGE_SLOT(gB, 16384, 0, 0);
  STAGE_SLOT(gA, 8192, 32, 0);
  STAGE_SLOT(gB, 24576, 32, 0);
  gA += 64; gB += 64;
  asm volatile("s_waitcnt vmcnt(4)" ::: "memory");
  __builtin_amdgcn_s_barrier();
  FENCE();

  floatx4 acc[8][4] = {};

  for (int kt = 0; kt < NT; ++kt) {
    const int cb = kt & 1;
    const int sbuf = cb ^ 1;
    const _Float16* lb = lds + cb * 32768;
    const bool st = (kt + 1 < NT);
    const bool last = (kt == NT - 1);

    half8 a[8], b[2];

#pragma unroll
    for (int i = 0; i < 8; ++i)
      a[i] = *reinterpret_cast<const half8*>(&lb[offA + i * 512]);
    b[0] = *reinterpret_cast<const half8*>(&lb[offB]);
    b[1] = *reinterpret_cast<const half8*>(&lb[offB + 512]);
    if (st) { STAGE_SLOT(gA, 0, 0, sbuf); }
    __builtin_amdgcn_s_barrier();
    FENCE();
    __builtin_amdgcn_s_setprio(1);
#pragma unroll
    for (int i = 0; i < 8; ++i) {
      acc[i][0] = __builtin_amdgcn_mfma_f32_16x16x32_f16(a[i], b[0], acc[i][0], 0, 0, 0);
      acc[i][1] = __builtin_amdgcn_mfma_f32_16x16x32_f16(a[i], b[1], acc[i][1], 0, 0, 0);
    }
    __builtin_amdgcn_s_setprio(0);
    __builtin_amdgcn_s_barrier();
    FENCE();

    b[0] = *reinterpret_cast<const half8*>(&lb[offB + 2 * 512]);
    b[1] = *reinterpret_cast<const half8*>(&lb[offB + 3 * 512]);
    if (st) { STAGE_SLOT(gB, 16384, 0, sbuf); }
    if (last) { asm volatile("s_waitcnt vmcnt(0)" ::: "memory"); }
    else      { asm volatile("s_waitcnt vmcnt(4)" ::: "memory"); }
    __builtin_amdgcn_s_barrier();
    FENCE();
    __builtin_amdgcn_s_setprio(1);
#pragma unroll
    for (int i = 0; i < 8; ++i) {
      acc[i][2] = __builtin_amdgcn_mfma_f32_16x16x32_f16(a[i], b[0], acc[i][2], 0, 0, 0);
      acc[i][3] = __builtin_amdgcn_mfma_f32_16x16x32_f16(a[i], b[1], acc[i][3], 0, 0, 0);
    }
    __builtin_amdgcn_s_setprio(0);
    __builtin_amdgcn_s_barrier();
    FENCE();

#pragma unroll
    for (int i = 0; i < 8; ++i)
      a[i] = *reinterpret_cast<const half8*>(&lb[8192 + offA + i * 512]);
    b[0] = *reinterpret_cast<const half8*>(&lb[8192 + offB]);
    b[1] = *reinterpret_cast<const half8*>(&lb[8192 + offB + 512]);
    if (st) { STAGE_SLOT(gA, 8192, 32, sbuf); }
    __builtin_amdgcn_s_barrier();
    FENCE();
    __builtin_amdgcn_s_setprio(1);
#pragma unroll
    for (int i = 0; i < 8; ++i) {
      acc[i][0] = __builtin_amdgcn_mfma_f32_16x16x32_f16(a[i], b[0], acc[i][0], 0, 0, 0);
      acc[i][1] = __builtin_amdgcn_mfma_f32_16x16x32_f16(a[i], b[1], acc[i][1], 0, 0, 0);
    }
    __builtin_amdgcn_s_setprio(0);
    __builtin_amdgcn_s_barrier();
    FENCE();

    b[0] = *reinterpret_cast<const half8*>(&lb[8192 + offB + 2 * 512]);
    b[1] = *reinterpret_cast<const half8*>(&lb[8192 + offB + 3 * 512]);
    if (st) { STAGE_SLOT(gB, 24576, 32, sbuf); gA += 64; gB += 64; }
    if (!last) { asm volatile("s_waitcnt vmcnt(4)" ::: "memory"); }
    __builtin_amdgcn_s_barrier();
    FENCE();
    __builtin_amdgcn_s_setprio(1);
#pragma unroll
    for (int i = 0; i < 8; ++i) {
      acc[i][2] = __builtin_amdgcn_mfma_f32_16x16x32_f16(a[i], b[0], acc[i][2], 0, 0, 0);
      acc[i][3] = __builtin_amdgcn_mfma_f32_16x16x32_f16(a[i], b[1], acc[i][3], 0, 0, 0);
    }
    __builtin_amdgcn_s_setprio(0);
    __builtin_amdgcn_s_barrier();
    FENCE();
  }
#undef STAGE_SLOT

  const int r0 = bm * 256 + wm * 128 + (lane >> 4) * 4;
  const int c0 = bn * 256 + wn * 64 + (lane & 15);
#pragma unroll
  for (int i = 0; i < 8; ++i) {
#pragma unroll
    for (int j2 = 0; j2 < 4; ++j2) {
#pragma unroll
      for (int ii = 0; ii < 4; ++ii) {
        const long idx = (long)(r0 + i * 16 + ii) * N + (c0 + j2 * 16);
        if (EPI == 0) {
          GH[idx] = (_Float16)acc[i][j2][ii];
        } else {
          OUT[idx] = acc[i][j2][ii];
        }
      }
    }
  }
}

extern "C" void kernel_launch(void* const* d_in, const int* in_sizes, int n_in,
                              void* d_out, int out_size, void* d_ws, size_t ws_size,
                              hipStream_t stream) {
  const float* x           = (const float*)d_in[0];
  const int*   gate_codes  = (const int*)d_in[1];
  const float* gate_scales = (const float*)d_in[2];
  const int*   up_codes    = (const int*)d_in[3];
  const float* up_scales   = (const float*)d_in[4];
  const int*   down_codes  = (const int*)d_in[5];
  const float* down_scales = (const float*)d_in[6];
  float* out = (float*)d_out;

  const long T = 8192, HD = 4096, M = 11008;

  // ws: x16 [T,HD] 67MB | Wg [M,HD] 90MB | Wu [M,HD] 90MB | gh [T,M] 180MB
  // (down-weights reuse Wg's slot after the fused kernel completes)
  char* ws = (char*)d_ws;
  _Float16* x16 = (_Float16*)ws;
  _Float16* Wg  = (_Float16*)(ws + T * HD * 2);
  _Float16* Wu  = (_Float16*)(ws + T * HD * 2 + M * HD * 2);
  _Float16* gh  = (_Float16*)(ws + T * HD * 2 + 2 * M * HD * 2);

  cvt_f32_to_f16_pad<<<2048, 256, 0, stream>>>(x, x16, (int)(T * HD / 8),
                                               (int)(HD / 8), (int)HD);
  dequant_nf4<<<2048, 256, 0, stream>>>(gate_codes, gate_scales, Wg,
                                        (int)(M * HD / 8), (int)HD, (int)(HD / 64),
                                        (int)HD);
  dequant_nf4<<<2048, 256, 0, stream>>>(up_codes, up_scales, Wu,
                                        (int)(M * HD / 8), (int)HD, (int)(HD / 64),
                                        (int)HD);

  // fused gate+up+SwiGLU: gh = silu(x@Wg^T) * (x@Wu^T)
  gemm_fused<4096, 4096, 11008><<<(8192 / 256) * (11008 / 128), 512, 0, stream>>>(
      x16, Wg, Wu, gh);

  // down: out = gh @ Wd^T (f32)
  dequant_nf4<<<2048, 256, 0, stream>>>(down_codes, down_scales, Wg,
                                        (int)(HD * M / 8), (int)M, (int)(M / 64),
                                        (int)M);
  gemm256<11008, 11008, 4096, 2><<<(8192 / 256) * (4096 / 256), 512, 0, stream>>>(
      gh, Wg, nullptr, out);
}